// Round 1
// baseline (205.573 us; speedup 1.0000x reference)
//
#include <hip/hip_runtime.h>
#include <hip/hip_bf16.h>

// B=2, N=512. Row index "row" = b*512 + i, rows 0..1023.
// EdgeConv factorization: e@W1 = x_i@(W1_top - W1_bot) + x_j@W1_bot
//   u_i = x_i@(W1_top - W1_bot) + b1 ; v_j = x_j@W1_bot ; h1 = relu(u_i + v_j)
// Masked max over neighbors only (A>0) is exact: h2 = relu(..) >= 0 > -1e9.

#define NEGV -1e9f

// Cooperative per-row EdgeConv core: block = 64 threads (1 wave), lane o owns
// output channel o. W2 column o held in 64 VGPRs; h1 shared via LDS broadcast.
__device__ __forceinline__ float edge_max(
    const float* __restrict__ A, const float* __restrict__ u,
    const float* __restrict__ v, const float* __restrict__ W2,
    const float* __restrict__ b2, int row, int o, float* h1) {
  float w[64];
#pragma unroll
  for (int k = 0; k < 64; k++) w[k] = W2[k * 64 + o];
  float ui = u[row * 64 + o];
  float bo = b2[o];
  int b = row >> 9, i = row & 511;
  const float* Arow = A + ((size_t)b * 512 + i) * 512;
  const float* vb = v + (size_t)b * 512 * 64;
  float acc = NEGV;
  for (int c = 0; c < 8; c++) {
    float aval = Arow[c * 64 + o];
    unsigned long long mask = __ballot(aval > 0.f);
    while (mask) {
      int j = c * 64 + __builtin_ctzll(mask);
      mask &= mask - 1;
      h1[o] = fmaxf(ui + vb[j * 64 + o], 0.f);
      __syncthreads();
      float s = bo;
      const float4* h4 = (const float4*)h1;
#pragma unroll
      for (int k4 = 0; k4 < 16; k4++) {
        float4 hv = h4[k4];
        s = fmaf(hv.x, w[4 * k4 + 0], s);
        s = fmaf(hv.y, w[4 * k4 + 1], s);
        s = fmaf(hv.z, w[4 * k4 + 2], s);
        s = fmaf(hv.w, w[4 * k4 + 3], s);
      }
      s = fmaxf(s, 0.f);
      acc = fmaxf(acc, s);
      __syncthreads();
    }
  }
  return acc;
}

// K1: per-node MLP (3->64->64), concat(node_features, center_score) -> x0[128],
// then u1/v1 for EdgeConv1 (F=128, W1 is [256][64]).
__global__ __launch_bounds__(64) void k1_node_uv(
    const float* __restrict__ coords, const float* __restrict__ nf,
    const float* __restrict__ cs,
    const float* __restrict__ Wh1, const float* __restrict__ bh1,
    const float* __restrict__ Wh2, const float* __restrict__ bh2,
    const float* __restrict__ W1, const float* __restrict__ b1,
    float* __restrict__ u, float* __restrict__ v) {
  int node = blockIdx.x;
  int o = threadIdx.x;
  __shared__ float t[64];
  __shared__ float xs[128];
  float c0 = coords[node * 3 + 0];
  float c1 = coords[node * 3 + 1];
  float c2 = coords[node * 3 + 2];
  float a = bh1[o];
  a = fmaf(c0, Wh1[0 * 64 + o], a);
  a = fmaf(c1, Wh1[1 * 64 + o], a);
  a = fmaf(c2, Wh1[2 * 64 + o], a);
  t[o] = fmaxf(a, 0.f);
  __syncthreads();
  float a2 = bh2[o];
#pragma unroll 8
  for (int k = 0; k < 64; k++) a2 = fmaf(t[k], Wh2[k * 64 + o], a2);
  xs[o] = fmaxf(a2, 0.f);
  if (o < 63) xs[64 + o] = nf[node * 63 + o];
  if (o == 63) xs[127] = cs[node];
  __syncthreads();
  float ua = b1[o], va = 0.f;
#pragma unroll 4
  for (int k = 0; k < 128; k++) {
    float xk = xs[k];
    float wt = W1[k * 64 + o];
    float wb = W1[(128 + k) * 64 + o];
    ua = fmaf(xk, wt - wb, ua);
    va = fmaf(xk, wb, va);
  }
  u[node * 64 + o] = ua;
  v[node * 64 + o] = va;
}

// K2/K3: EdgeConv (max over neighbors) + optional residual for the value fed
// forward; writes raw (pre-residual) output and u/v for the next EdgeConv
// (F=64, W1n is [128][64]).
__global__ __launch_bounds__(64) void k_edgeconv_uv(
    const float* __restrict__ A, const float* __restrict__ u,
    const float* __restrict__ v, const float* __restrict__ W2,
    const float* __restrict__ b2,
    const float* __restrict__ res,  // may be null
    float* __restrict__ raw_out,
    const float* __restrict__ W1n, const float* __restrict__ b1n,
    float* __restrict__ un, float* __restrict__ vn) {
  __shared__ float h1[64];
  __shared__ float xs[64];
  int row = blockIdx.x, o = threadIdx.x;
  float acc = edge_max(A, u, v, W2, b2, row, o, h1);
  raw_out[row * 64 + o] = acc;
  float xv = acc + (res ? res[row * 64 + o] : 0.f);
  xs[o] = xv;
  __syncthreads();
  float ua = b1n[o], va = 0.f;
#pragma unroll 4
  for (int k = 0; k < 64; k++) {
    float xk = xs[k];
    float wt = W1n[k * 64 + o];
    float wb = W1n[(64 + k) * 64 + o];
    ua = fmaf(xk, wt - wb, ua);
    va = fmaf(xk, wb, va);
  }
  un[row * 64 + o] = ua;
  vn[row * 64 + o] = va;
}

// K4: EdgeConv3 + residual(ec2_raw) + head MLP 64->128->3 (both relu).
__global__ __launch_bounds__(64) void k_edgeconv_final(
    const float* __restrict__ A, const float* __restrict__ u,
    const float* __restrict__ v, const float* __restrict__ W2,
    const float* __restrict__ b2, const float* __restrict__ res,
    const float* __restrict__ Wh6, const float* __restrict__ bh6,
    const float* __restrict__ Wout, const float* __restrict__ bout,
    float* __restrict__ out) {
  __shared__ float h1[64];
  __shared__ float xs[64];
  __shared__ float h6[128];
  int row = blockIdx.x, o = threadIdx.x;
  float acc = edge_max(A, u, v, W2, b2, row, o, h1);
  xs[o] = acc + res[row * 64 + o];
  __syncthreads();
  float s0 = bh6[o], s1 = bh6[64 + o];
#pragma unroll 4
  for (int k = 0; k < 64; k++) {
    float xk = xs[k];
    s0 = fmaf(xk, Wh6[k * 128 + o], s0);
    s1 = fmaf(xk, Wh6[k * 128 + 64 + o], s1);
  }
  h6[o] = fmaxf(s0, 0.f);
  h6[64 + o] = fmaxf(s1, 0.f);
  __syncthreads();
  if (o < 3) {
    float s = bout[o];
#pragma unroll 8
    for (int k = 0; k < 128; k++) s = fmaf(h6[k], Wout[k * 3 + o], s);
    out[row * 3 + o] = fmaxf(s, 0.f);
  }
}

extern "C" void kernel_launch(void* const* d_in, const int* in_sizes, int n_in,
                              void* d_out, int out_size, void* d_ws,
                              size_t ws_size, hipStream_t stream) {
  const float* coords = (const float*)d_in[0];
  const float* A      = (const float*)d_in[1];
  const float* nf     = (const float*)d_in[2];
  const float* cs     = (const float*)d_in[3];
  const float* Wh1 = (const float*)d_in[4];
  const float* bh1 = (const float*)d_in[5];
  const float* Wh2 = (const float*)d_in[6];
  const float* bh2 = (const float*)d_in[7];
  const float* e1W1 = (const float*)d_in[8];
  const float* e1b1 = (const float*)d_in[9];
  const float* e1W2 = (const float*)d_in[10];
  const float* e1b2 = (const float*)d_in[11];
  const float* e2W1 = (const float*)d_in[12];
  const float* e2b1 = (const float*)d_in[13];
  const float* e2W2 = (const float*)d_in[14];
  const float* e2b2 = (const float*)d_in[15];
  const float* e3W1 = (const float*)d_in[16];
  const float* e3b1 = (const float*)d_in[17];
  const float* e3W2 = (const float*)d_in[18];
  const float* e3b2 = (const float*)d_in[19];
  const float* Wh6 = (const float*)d_in[20];
  const float* bh6 = (const float*)d_in[21];
  const float* Wout = (const float*)d_in[22];
  const float* bout = (const float*)d_in[23];

  float* ws = (float*)d_ws;
  // layout (floats): u1, v1 (65536 each), ec1_out, u2, v2, ec2_raw, u3, v3
  float* u1  = ws + 0;
  float* v1  = ws + 65536;
  float* e1o = ws + 131072;
  float* u2  = ws + 196608;
  float* v2  = ws + 262144;
  float* e2r = ws + 327680;
  float* u3  = ws + 393216;
  float* v3  = ws + 458752;
  float* out = (float*)d_out;

  dim3 grid(1024), blk(64);
  k1_node_uv<<<grid, blk, 0, stream>>>(coords, nf, cs, Wh1, bh1, Wh2, bh2,
                                       e1W1, e1b1, u1, v1);
  k_edgeconv_uv<<<grid, blk, 0, stream>>>(A, u1, v1, e1W2, e1b2, nullptr, e1o,
                                          e2W1, e2b1, u2, v2);
  k_edgeconv_uv<<<grid, blk, 0, stream>>>(A, u2, v2, e2W2, e2b2, e1o, e2r,
                                          e3W1, e3b1, u3, v3);
  k_edgeconv_final<<<grid, blk, 0, stream>>>(A, u3, v3, e3W2, e3b2, e2r, Wh6,
                                             bh6, Wout, bout, out);
}

// Round 2
// 171.913 us; speedup vs baseline: 1.1958x; 1.1958x over previous
//
#include <hip/hip_runtime.h>
#include <hip/hip_bf16.h>

// B=2, N=512. Row "row" = b*512 + i, rows 0..1023.
// EdgeConv factorization: e@W1 = x_i@(W1_top - W1_bot) + x_j@W1_bot
//   u_i = x_i@(W1_top-W1_bot)+b1 ; v_j = x_j@W1_bot ; h1 = relu(u_i+v_j)
// Masked max over neighbors only (A>0) is exact: h2 = relu(..) >= 0 > -1e9.
// Neighbor lists built once in k1 (same adjacency for all 3 EdgeConvs).

#define NEGV -1e9f
#define MAXNBR 96

// EdgeConv core: 1 wave (64 threads), lane o owns output channel o.
// Edges in groups of 4; next group's v-loads prefetched while current group
// runs 4 interleaved GEMVs (ILP 4) off LDS-broadcast h1 buffers.
__device__ __forceinline__ float edge_max2(
    const int* __restrict__ nbrL, int cnt, const float* __restrict__ vb,
    float ui, float bo, const float* __restrict__ w, int o,
    float (*bufs)[64]) {
  float acc = NEGV;
  float vl[4];
#pragma unroll
  for (int t = 0; t < 4; t++) {
    int e = t < cnt ? t : cnt - 1;
    vl[t] = vb[nbrL[e] * 64 + o];
  }
  for (int e0 = 0; e0 < cnt; e0 += 4) {
    float cur[4];
#pragma unroll
    for (int t = 0; t < 4; t++) cur[t] = vl[t];
    if (e0 + 4 < cnt) {
#pragma unroll
      for (int t = 0; t < 4; t++) {
        int e = e0 + 4 + t;
        if (e >= cnt) e = cnt - 1;
        vl[t] = vb[nbrL[e] * 64 + o];  // prefetch next group
      }
    }
#pragma unroll
    for (int t = 0; t < 4; t++) bufs[t][o] = fmaxf(ui + cur[t], 0.f);
    __syncthreads();
    float s0 = bo, s1 = bo, s2 = bo, s3 = bo;
    const float4* b0 = (const float4*)bufs[0];
    const float4* b1 = (const float4*)bufs[1];
    const float4* b2 = (const float4*)bufs[2];
    const float4* b3 = (const float4*)bufs[3];
#pragma unroll
    for (int k4 = 0; k4 < 16; k4++) {
      float4 r0 = b0[k4], r1 = b1[k4], r2 = b2[k4], r3 = b3[k4];
      float w0 = w[4 * k4 + 0], w1 = w[4 * k4 + 1];
      float w2v = w[4 * k4 + 2], w3 = w[4 * k4 + 3];
      s0 = fmaf(r0.x, w0, s0); s0 = fmaf(r0.y, w1, s0);
      s0 = fmaf(r0.z, w2v, s0); s0 = fmaf(r0.w, w3, s0);
      s1 = fmaf(r1.x, w0, s1); s1 = fmaf(r1.y, w1, s1);
      s1 = fmaf(r1.z, w2v, s1); s1 = fmaf(r1.w, w3, s1);
      s2 = fmaf(r2.x, w0, s2); s2 = fmaf(r2.y, w1, s2);
      s2 = fmaf(r2.z, w2v, s2); s2 = fmaf(r2.w, w3, s2);
      s3 = fmaf(r3.x, w0, s3); s3 = fmaf(r3.y, w1, s3);
      s3 = fmaf(r3.z, w2v, s3); s3 = fmaf(r3.w, w3, s3);
    }
    acc = fmaxf(acc, fmaxf(s0, 0.f));
    if (e0 + 1 < cnt) acc = fmaxf(acc, fmaxf(s1, 0.f));
    if (e0 + 2 < cnt) acc = fmaxf(acc, fmaxf(s2, 0.f));
    if (e0 + 3 < cnt) acc = fmaxf(acc, fmaxf(s3, 0.f));
    __syncthreads();
  }
  return acc;
}

// K1: neighbor-list build + node MLP (3->64->64) + concat -> x0[128] + u1/v1.
__global__ __launch_bounds__(64) void k1_node_uv(
    const float* __restrict__ coords, const float* __restrict__ A,
    const float* __restrict__ nf, const float* __restrict__ cs,
    const float* __restrict__ Wh1, const float* __restrict__ bh1,
    const float* __restrict__ Wh2, const float* __restrict__ bh2,
    const float* __restrict__ W1, const float* __restrict__ b1,
    float* __restrict__ u, float* __restrict__ v,
    int* __restrict__ nbrCnt, int* __restrict__ nbrG) {
  int node = blockIdx.x;
  int o = threadIdx.x;
  __shared__ float t[64];
  __shared__ float xs[128];
  // ---- neighbor list build (ballot + rank compaction) ----
  {
    const float* Arow = A + (size_t)node * 512;
    int base = 0;
    for (int c = 0; c < 8; c++) {
      float aval = Arow[c * 64 + o];
      bool p = aval > 0.f;
      unsigned long long m = __ballot(p);
      if (p) {
        int pos = base + __builtin_popcountll(m & ((1ull << o) - 1ull));
        if (pos < MAXNBR) nbrG[node * MAXNBR + pos] = c * 64 + o;
      }
      base += __builtin_popcountll(m);
    }
    if (o == 0) nbrCnt[node] = base < MAXNBR ? base : MAXNBR;
  }
  // ---- node MLP ----
  float c0 = coords[node * 3 + 0];
  float c1 = coords[node * 3 + 1];
  float c2 = coords[node * 3 + 2];
  float a = bh1[o];
  a = fmaf(c0, Wh1[0 * 64 + o], a);
  a = fmaf(c1, Wh1[1 * 64 + o], a);
  a = fmaf(c2, Wh1[2 * 64 + o], a);
  t[o] = fmaxf(a, 0.f);
  __syncthreads();
  float a2 = bh2[o];
#pragma unroll 8
  for (int k = 0; k < 64; k++) a2 = fmaf(t[k], Wh2[k * 64 + o], a2);
  xs[o] = fmaxf(a2, 0.f);
  if (o < 63) xs[64 + o] = nf[node * 63 + o];
  if (o == 63) xs[127] = cs[node];
  __syncthreads();
  float ua = b1[o], va = 0.f;
#pragma unroll 4
  for (int k = 0; k < 128; k++) {
    float xk = xs[k];
    float wt = W1[k * 64 + o];
    float wb = W1[(128 + k) * 64 + o];
    ua = fmaf(xk, wt - wb, ua);
    va = fmaf(xk, wb, va);
  }
  u[node * 64 + o] = ua;
  v[node * 64 + o] = va;
}

// K2/K3: EdgeConv + optional residual; writes raw out and u/v for next layer.
__global__ __launch_bounds__(64) void k_edgeconv_uv(
    const int* __restrict__ nbrCnt, const int* __restrict__ nbrG,
    const float* __restrict__ u, const float* __restrict__ v,
    const float* __restrict__ W2, const float* __restrict__ b2,
    const float* __restrict__ res,  // may be null
    float* __restrict__ raw_out,
    const float* __restrict__ W1n, const float* __restrict__ b1n,
    float* __restrict__ un, float* __restrict__ vn) {
  __shared__ int nbrL[MAXNBR];
  __shared__ float bufs[4][64];
  __shared__ float xs[64];
  int row = blockIdx.x, o = threadIdx.x;
  int cnt = __builtin_amdgcn_readfirstlane(nbrCnt[row]);
  for (int t = o; t < MAXNBR; t += 64)
    nbrL[t] = (t < cnt) ? nbrG[row * MAXNBR + t] : 0;
  float w[64];
#pragma unroll
  for (int k = 0; k < 64; k++) w[k] = W2[k * 64 + o];
  float ui = u[row * 64 + o];
  float bo = b2[o];
  const float* vb = v + (size_t)(row >> 9) * 512 * 64;
  __syncthreads();
  float acc = edge_max2(nbrL, cnt, vb, ui, bo, w, o, bufs);
  raw_out[row * 64 + o] = acc;
  xs[o] = acc + (res ? res[row * 64 + o] : 0.f);
  __syncthreads();
  float ua = b1n[o], va = 0.f;
#pragma unroll 4
  for (int k = 0; k < 64; k++) {
    float xk = xs[k];
    float wt = W1n[k * 64 + o];
    float wb = W1n[(64 + k) * 64 + o];
    ua = fmaf(xk, wt - wb, ua);
    va = fmaf(xk, wb, va);
  }
  un[row * 64 + o] = ua;
  vn[row * 64 + o] = va;
}

// K4: EdgeConv3 + residual(ec2_raw) + head MLP 64->128->3 (both relu).
__global__ __launch_bounds__(64) void k_edgeconv_final(
    const int* __restrict__ nbrCnt, const int* __restrict__ nbrG,
    const float* __restrict__ u, const float* __restrict__ v,
    const float* __restrict__ W2, const float* __restrict__ b2,
    const float* __restrict__ res,
    const float* __restrict__ Wh6, const float* __restrict__ bh6,
    const float* __restrict__ Wout, const float* __restrict__ bout,
    float* __restrict__ out) {
  __shared__ int nbrL[MAXNBR];
  __shared__ float bufs[4][64];
  __shared__ float xs[64];
  __shared__ float h6[128];
  int row = blockIdx.x, o = threadIdx.x;
  int cnt = __builtin_amdgcn_readfirstlane(nbrCnt[row]);
  for (int t = o; t < MAXNBR; t += 64)
    nbrL[t] = (t < cnt) ? nbrG[row * MAXNBR + t] : 0;
  float w[64];
#pragma unroll
  for (int k = 0; k < 64; k++) w[k] = W2[k * 64 + o];
  float ui = u[row * 64 + o];
  float bo = b2[o];
  const float* vb = v + (size_t)(row >> 9) * 512 * 64;
  __syncthreads();
  float acc = edge_max2(nbrL, cnt, vb, ui, bo, w, o, bufs);
  xs[o] = acc + res[row * 64 + o];
  __syncthreads();
  float s0 = bh6[o], s1 = bh6[64 + o];
#pragma unroll 4
  for (int k = 0; k < 64; k++) {
    float xk = xs[k];
    s0 = fmaf(xk, Wh6[k * 128 + o], s0);
    s1 = fmaf(xk, Wh6[k * 128 + 64 + o], s1);
  }
  h6[o] = fmaxf(s0, 0.f);
  h6[64 + o] = fmaxf(s1, 0.f);
  __syncthreads();
  if (o < 3) {
    float s = bout[o];
#pragma unroll 8
    for (int k = 0; k < 128; k++) s = fmaf(h6[k], Wout[k * 3 + o], s);
    out[row * 3 + o] = fmaxf(s, 0.f);
  }
}

extern "C" void kernel_launch(void* const* d_in, const int* in_sizes, int n_in,
                              void* d_out, int out_size, void* d_ws,
                              size_t ws_size, hipStream_t stream) {
  const float* coords = (const float*)d_in[0];
  const float* A      = (const float*)d_in[1];
  const float* nf     = (const float*)d_in[2];
  const float* cs     = (const float*)d_in[3];
  const float* Wh1 = (const float*)d_in[4];
  const float* bh1 = (const float*)d_in[5];
  const float* Wh2 = (const float*)d_in[6];
  const float* bh2 = (const float*)d_in[7];
  const float* e1W1 = (const float*)d_in[8];
  const float* e1b1 = (const float*)d_in[9];
  const float* e1W2 = (const float*)d_in[10];
  const float* e1b2 = (const float*)d_in[11];
  const float* e2W1 = (const float*)d_in[12];
  const float* e2b1 = (const float*)d_in[13];
  const float* e2W2 = (const float*)d_in[14];
  const float* e2b2 = (const float*)d_in[15];
  const float* e3W1 = (const float*)d_in[16];
  const float* e3b1 = (const float*)d_in[17];
  const float* e3W2 = (const float*)d_in[18];
  const float* e3b2 = (const float*)d_in[19];
  const float* Wh6 = (const float*)d_in[20];
  const float* bh6 = (const float*)d_in[21];
  const float* Wout = (const float*)d_in[22];
  const float* bout = (const float*)d_in[23];

  float* ws = (float*)d_ws;
  // float region: u1,v1,e1o,u2,v2,e2r,u3,v3 (65536 each = 524288 floats)
  float* u1  = ws + 0;
  float* v1  = ws + 65536;
  float* e1o = ws + 131072;
  float* u2  = ws + 196608;
  float* v2  = ws + 262144;
  float* e2r = ws + 327680;
  float* u3  = ws + 393216;
  float* v3  = ws + 458752;
  int* wsI = (int*)(ws + 524288);
  int* nbrCnt = wsI;            // 1024 ints
  int* nbrG   = wsI + 1024;     // 1024*96 ints
  float* out = (float*)d_out;

  dim3 grid(1024), blk(64);
  k1_node_uv<<<grid, blk, 0, stream>>>(coords, A, nf, cs, Wh1, bh1, Wh2, bh2,
                                       e1W1, e1b1, u1, v1, nbrCnt, nbrG);
  k_edgeconv_uv<<<grid, blk, 0, stream>>>(nbrCnt, nbrG, u1, v1, e1W2, e1b2,
                                          nullptr, e1o, e2W1, e2b1, u2, v2);
  k_edgeconv_uv<<<grid, blk, 0, stream>>>(nbrCnt, nbrG, u2, v2, e2W2, e2b2,
                                          e1o, e2r, e3W1, e3b1, u3, v3);
  k_edgeconv_final<<<grid, blk, 0, stream>>>(nbrCnt, nbrG, u3, v3, e3W2, e3b2,
                                             e2r, Wh6, bh6, Wout, bout, out);
}